// Round 7
// baseline (341.920 us; speedup 1.0000x reference)
//
#include <hip/hip_runtime.h>
#include <hip/hip_fp16.h>
#include <math.h>

#define B   4
#define V   360
#define D   512
#define ENC 64
#define CH  9
#define P2  4096
#define NCHUNK 90
#define VCHUNK 4     // 360 / 90
#define RECH 16      // halfs per plain record (32 B) -- fallback layout
#define PENT 513     // pair-table entries per detector row
#define PENTB 64     // bytes per pair entry: [A ch0-7 |16| B ch0-7 |32| A8 |34| B8 |36| pad]

// ---------------------------------------------------------------------------
// Kernel 1: 3x3 conv (pad 1). 720 blocks (2 rows x 128thr x 4px), weights
// staged to LDS once per block (broadcast ds_read_b128, no SMEM stalls),
// feat rows register double-buffered over ic.
// ---------------------------------------------------------------------------
template <int PAIR>
__global__ __launch_bounds__(256) void conv_kernel(
    const float* __restrict__ feat,   // [B,ENC,V,D]
    const float* __restrict__ w,      // [CH,ENC,3,3]
    const float* __restrict__ bias,   // [CH]
    char* __restrict__ outp)
{
    __shared__ float wl[ENC * CH * 12];   // [ic][oc][12] (16B-aligned rows)
    for (int i = threadIdx.x; i < ENC * CH * 9; i += 256) {
        const int oc  = i / (ENC * 9);
        const int rem = i - oc * (ENC * 9);
        const int ic  = rem / 9;
        const int k   = rem - ic * 9;
        wl[(ic * CH + oc) * 12 + k] = w[i];
    }
    __syncthreads();

    const int bid = blockIdx.x;               // 720 = 8 * 90, bijective swizzle
    const int sw  = (bid & 7) * 90 + (bid >> 3);
    const int b   = sw / 180;                 // batch b -> XCDs {2b,2b+1}
    const int vt  = sw % 180;
    const int tr  = threadIdx.x >> 7;         // row within tile: 0..1
    const int v   = vt * 2 + tr;
    const int d0  = (threadIdx.x & 127) * 4;  // 0..508

    float acc[CH][4];
    #pragma unroll
    for (int oc = 0; oc < CH; ++oc) {
        const float bv = bias[oc];
        #pragma unroll
        for (int p = 0; p < 4; ++p) acc[oc][p] = bv;
    }

    const float* fb = feat + ((size_t)b * ENC * V + v) * D + d0;
    const bool vm = v > 0, vp = v < V - 1;
    const bool dm = d0 > 0, dp = d0 + 4 < D;

    float r0[3][6], r1[3][6];   // taps [d0-1 .. d0+4] x 3 rows

    auto ld = [&](float r[3][6], int ic) {
        const float* f = fb + (size_t)ic * (V * D);
        #pragma unroll
        for (int rr = 0; rr < 3; ++rr) {
            const float* fr = f + (rr - 1) * D;
            const bool ok = (rr == 0) ? vm : ((rr == 2) ? vp : true);
            float4 c = ok ? *(const float4*)fr : float4{0.f, 0.f, 0.f, 0.f};
            r[rr][1] = c.x; r[rr][2] = c.y; r[rr][3] = c.z; r[rr][4] = c.w;
            r[rr][0] = (ok && dm) ? fr[-1] : 0.f;
            r[rr][5] = (ok && dp) ? fr[4]  : 0.f;
        }
    };
    auto fmab = [&](const float r[3][6], int ic) {
        #pragma unroll
        for (int oc = 0; oc < CH; ++oc) {
            const float* wp = &wl[(ic * CH + oc) * 12];  // wave-uniform -> broadcast
            const float4 wA = *(const float4*)wp;
            const float4 wB = *(const float4*)(wp + 4);
            const float  w8 = wp[8];
            const float wk[9] = {wA.x, wA.y, wA.z, wA.w, wB.x, wB.y, wB.z, wB.w, w8};
            #pragma unroll
            for (int kr = 0; kr < 3; ++kr) {
                #pragma unroll
                for (int kc = 0; kc < 3; ++kc) {
                    const float wv = wk[kr * 3 + kc];
                    #pragma unroll
                    for (int p = 0; p < 4; ++p)
                        acc[oc][p] = fmaf(r[kr][p + kc], wv, acc[oc][p]);
                }
            }
        }
    };

    ld(r0, 0);
    #pragma unroll 1
    for (int ic = 0; ic < ENC; ic += 2) {
        ld(r1, ic + 1);                 // prefetch next ic while computing
        fmab(r0, ic);
        if (ic + 2 < ENC) ld(r0, ic + 2);
        fmab(r1, ic + 1);
    }

    #pragma unroll
    for (int p = 0; p < 4; ++p) {
        union { __half2 h; unsigned u; } cv;
        uint4 pk;
        cv.h = __floats2half2_rn(acc[0][p], acc[1][p]); pk.x = cv.u;
        cv.h = __floats2half2_rn(acc[2][p], acc[3][p]); pk.y = cv.u;
        cv.h = __floats2half2_rn(acc[4][p], acc[5][p]); pk.z = cv.u;
        cv.h = __floats2half2_rn(acc[6][p], acc[7][p]); pk.w = cv.u;
        cv.h = __floats2half2_rn(acc[8][p], 0.f);
        const unsigned short z = (unsigned short)(cv.u & 0xffffu);
        const int x = d0 + p;
        if (PAIR) {
            char* row = outp + (size_t)(b * V + v) * PENT * PENTB;
            char* eA = row + (size_t)(x + 1) * PENTB;       // A-half of entry x+1
            *(uint4*)eA = pk;
            *(unsigned short*)(eA + 32) = z;
            char* eB = row + (size_t)x * PENTB + 16;        // B-half of entry x
            *(uint4*)eB = pk;
            *(unsigned short*)(eB + 18) = z;                // byte 34 of entry
            if (x == 0) {                                   // entry 0: A = rec[0]
                *(uint4*)row = pk;
                *(unsigned short*)(row + 32) = z;
            }
            if (x == D - 1) {                               // entry 512: B = rec[511]
                char* eC = row + (size_t)512 * PENTB + 16;
                *(uint4*)eC = pk;
                *(unsigned short*)(eC + 18) = z;
            }
        } else {
            __half* rec = (__half*)outp + (size_t)(((size_t)b * V + v) * D + x) * RECH;
            *(uint4*)rec = pk;
            *(unsigned*)(rec + 8) = (unsigned)z;
        }
    }
}

// ---------------------------------------------------------------------------
// Kernel 1b: paired sinogram table  sg2[b,v,x] = (sg[x], sg[min(x+1,D-1)])
// ---------------------------------------------------------------------------
__global__ __launch_bounds__(256) void build_sg2(
    const float* __restrict__ sg, float2* __restrict__ sg2)
{
    const int i = blockIdx.x * 256 + threadIdx.x;  // B*V*D = 737280 = 2880*256
    const int x = i & (D - 1);
    const float a = sg[i];
    const float c = (x == D - 1) ? a : sg[i + 1];
    sg2[i] = float2{a, c};
}

// ---------------------------------------------------------------------------
// Shared math: Fourier decode of one record
// ---------------------------------------------------------------------------
__device__ __forceinline__ float decode_rec(uint4 a, unsigned short z, float rel)
{
    float q[9];
    union { unsigned uu; __half2 h; } c;
    float2 f;
    c.uu = a.x; f = __half22float2(c.h); q[0] = f.x; q[1] = f.y;
    c.uu = a.y; f = __half22float2(c.h); q[2] = f.x; q[3] = f.y;
    c.uu = a.z; f = __half22float2(c.h); q[4] = f.x; q[5] = f.y;
    c.uu = a.w; f = __half22float2(c.h); q[6] = f.x; q[7] = f.y;
    union { unsigned short us; __half hh; } c2;
    c2.us = z;
    q[8] = __half2float(c2.hh);

    const float ang = rel * 1.5707963267948966f;  // OMEGA
    float s1, c1;
    __sincosf(ang, &s1, &c1);
    const float c2f = fmaf(2.f * c1, c1, -1.f);
    const float s2f = 2.f * c1 * s1;
    const float c3f = fmaf(2.f * c1, c2f, -c1);
    const float s3f = fmaf(2.f * c1, s2f, -s1);
    const float c4f = fmaf(2.f * c1, c3f, -c2f);
    const float s4f = fmaf(2.f * c1, s3f, -s2f);

    float vv = q[0];
    vv = fmaf(q[1], c1,  vv); vv = fmaf(q[2], c2f, vv);
    vv = fmaf(q[3], c3f, vv); vv = fmaf(q[4], c4f, vv);
    vv = fmaf(q[5], s1,  vv); vv = fmaf(q[6], s2f, vv);
    vv = fmaf(q[7], s3f, vv); vv = fmaf(q[8], s4f, vv);
    return vv;
}

// ---------------------------------------------------------------------------
// Kernel 2 (pair path): xm/xp independent (tie-safe); one 64B line common
// case. sched_barrier keeps ALL gathers in flight before any decode math.
// ---------------------------------------------------------------------------
__global__ __launch_bounds__(256) void sample_pair(
    const char* __restrict__ pair,       // [B,V,PENT,64B]
    const float2* __restrict__ sg2,      // [B,V,D] paired
    const float* __restrict__ grid,      // [B,V,P2,2]
    const float* __restrict__ sq,        // [B,1,V,P2]
    float* __restrict__ partial)         // [NCHUNK,B,P2]
{
    const int bid = blockIdx.x;          // 5760 = 8 XCDs * 720
    const int xcd = bid & 7;
    const int b   = xcd >> 1;            // batch b owned by XCDs {2b,2b+1}
    const int idx = ((bid >> 3) << 1) | (xcd & 1);  // 0..1439
    const int chunk = idx >> 4;                     // 0..89
    const int p  = (idx & 15) * 256 + threadIdx.x;
    const int v0 = chunk * VCHUNK;

    const char*   pb  = pair + (size_t)b * V * PENT * PENTB;
    const float2* s2b = sg2 + (size_t)b * V * D;

    // ---- phase A: coalesced streaming loads --------------------------------
    float gx[4], gy[4], sv[4];
    #pragma unroll
    for (int u = 0; u < 4; ++u) {
        const size_t gi = (size_t)(b * V + v0 + u) * P2 + p;
        const double gd = __builtin_nontemporal_load((const double*)grid + gi);
        const unsigned long long gu = __double_as_longlong(gd);
        gx[u] = __uint_as_float((unsigned)gu);
        gy[u] = __uint_as_float((unsigned)(gu >> 32));
        sv[u] = __builtin_nontemporal_load(sq + gi);
    }

    // ---- phase B: pair-entry gathers (1 line / point common case) ----------
    uint4 qa[4], qb[4];
    unsigned short zA[4], zB[4];
    float relm[4], relp[4];
    #pragma unroll
    for (int u = 0; u < 4; ++u) {
        const float fy = ((gy[u] + 1e-6f + 1.f) * (float)V - 1.f) * 0.5f;
        const int   yi = (int)fminf(fmaxf(rintf(fy), 0.f), (float)(V - 1));
        const float fx0 = ((gx[u] + 1e-6f + 1.f) * (float)D - 1.f) * 0.5f;
        const int xm = (int)fminf(fmaxf(rintf(fx0 - 0.5f), 0.f), (float)(D - 1));
        const int xp = (int)fminf(fmaxf(rintf(fx0 + 0.5f), 0.f), (float)(D - 1));
        const float qcm = ((float)xm + 0.5f) * (2.f / (float)D) - 1.f;
        const float qcp = ((float)xp + 0.5f) * (2.f / (float)D) - 1.f;
        relm[u] = (gx[u] - qcm) * (float)D;
        relp[u] = (gx[u] - qcp) * (float)D;
        const char* rowp = pb + (size_t)yi * (PENT * PENTB);
        const char* e1 = rowp + (size_t)(xm + 1) * PENTB;   // A-half = rec[xm]
        const char* e2 = rowp + (size_t)xp * PENTB;         // B-half = rec[xp]
        qa[u] = *(const uint4*)e1;
        zA[u] = *(const unsigned short*)(e1 + 32);
        qb[u] = *(const uint4*)(e2 + 16);
        zB[u] = *(const unsigned short*)(e2 + 34);
    }

    // ---- phase C: bilinear gathers -----------------------------------------
    float bl00[4], bl01[4], bl10[4], bl11[4], wxv[4], wyv[4];
    #pragma unroll
    for (int u = 0; u < 4; ++u) {
        float fxb = fminf(fmaxf(((gx[u] + 1.f) * (float)D - 1.f) * 0.5f, 0.f), (float)(D - 1));
        float fyb = fminf(fmaxf(((gy[u] + 1.f) * (float)V - 1.f) * 0.5f, 0.f), (float)(V - 1));
        const float x0 = floorf(fxb), y0 = floorf(fyb);
        wxv[u] = fxb - x0; wyv[u] = fyb - y0;
        const int x0i = (int)x0, y0i = (int)y0;
        const int y1i = min(y0i + 1, V - 1);
        const float2 t  = s2b[y0i * D + x0i];
        const float2 u2 = s2b[y1i * D + x0i];
        bl00[u] = t.x;  bl01[u] = t.y;
        bl10[u] = u2.x; bl11[u] = u2.y;
    }

    // Keep every gather above in flight before any math below.
    __builtin_amdgcn_sched_barrier(0);

    // ---- phase D: math ------------------------------------------------------
    float acc = 0.f;
    #pragma unroll
    for (int u = 0; u < 4; ++u) {
        const float vmv = decode_rec(qa[u], zA[u], relm[u]);
        const float vpv = decode_rec(qb[u], zB[u], relp[u]);
        const float lm = fabsf(relm[u]) + 1e-4f;
        const float lp = fabsf(relp[u]) + 1e-4f;
        const float recon = (vmv * lp + vpv * lm) / (lm + lp);

        const float wx = wxv[u], wy = wyv[u];
        const float bp = bl00[u] * (1.f - wx) * (1.f - wy) + bl01[u] * wx * (1.f - wy)
                       + bl10[u] * (1.f - wx) * wy         + bl11[u] * wx * wy;

        acc += (recon + bp) * sv[u] * 1e4f;
    }
    __builtin_nontemporal_store(acc, partial + ((size_t)chunk * B + b) * P2 + p);
}

// ---------------------------------------------------------------------------
// Kernel 2 fallback: plain 32B records
// ---------------------------------------------------------------------------
template <int PAIRED>
__global__ __launch_bounds__(256) void sample_basic(
    const __half* __restrict__ sino,     // [B,V,D,RECH]
    const float* __restrict__ sinogram,  // [B,1,V,D]
    const float2* __restrict__ sg2,      // [B,V,D] paired
    const float* __restrict__ grid,
    const float* __restrict__ sq,
    float* __restrict__ partial)
{
    const int bid = blockIdx.x;
    const int xcd = bid & 7;
    const int b   = xcd >> 1;
    const int idx = ((bid >> 3) << 1) | (xcd & 1);
    const int chunk = idx >> 4;
    const int p  = (idx & 15) * 256 + threadIdx.x;
    const int v0 = chunk * VCHUNK;

    const float*  sg   = sinogram + (size_t)b * V * D;
    const float2* s2b  = sg2 + (size_t)b * V * D;
    const __half* sb   = sino + (size_t)b * V * D * RECH;

    float gx[4], gy[4], sv[4];
    #pragma unroll
    for (int u = 0; u < 4; ++u) {
        const size_t gi = (size_t)(b * V + v0 + u) * P2 + p;
        const double gd = __builtin_nontemporal_load((const double*)grid + gi);
        const unsigned long long gu = __double_as_longlong(gd);
        gx[u] = __uint_as_float((unsigned)gu);
        gy[u] = __uint_as_float((unsigned)(gu >> 32));
        sv[u] = __builtin_nontemporal_load(sq + gi);
    }

    uint4    ra[4][2];
    unsigned rz[4][2];
    float    rel[4][2];
    #pragma unroll
    for (int u = 0; u < 4; ++u) {
        const float fy = ((gy[u] + 1e-6f + 1.f) * (float)V - 1.f) * 0.5f;
        const int   yi = (int)fminf(fmaxf(rintf(fy), 0.f), (float)(V - 1));
        const float fx0 = ((gx[u] + 1e-6f + 1.f) * (float)D - 1.f) * 0.5f;
        #pragma unroll
        for (int sft = 0; sft < 2; ++sft) {
            const float fx = (sft == 0) ? (fx0 - 0.5f) : (fx0 + 0.5f);
            const int   xi = (int)fminf(fmaxf(rintf(fx), 0.f), (float)(D - 1));
            const float qc = ((float)xi + 0.5f) * (2.f / (float)D) - 1.f;
            rel[u][sft] = (gx[u] - qc) * (float)D;
            const __half* rec = sb + (size_t)(yi * D + xi) * RECH;
            ra[u][sft] = *(const uint4*)rec;
            rz[u][sft] = *(const unsigned*)(rec + 8);
        }
    }

    float bl00[4], bl01[4], bl10[4], bl11[4], wxv[4], wyv[4];
    #pragma unroll
    for (int u = 0; u < 4; ++u) {
        float fxb = fminf(fmaxf(((gx[u] + 1.f) * (float)D - 1.f) * 0.5f, 0.f), (float)(D - 1));
        float fyb = fminf(fmaxf(((gy[u] + 1.f) * (float)V - 1.f) * 0.5f, 0.f), (float)(V - 1));
        const float x0 = floorf(fxb), y0 = floorf(fyb);
        wxv[u] = fxb - x0; wyv[u] = fyb - y0;
        const int x0i = (int)x0, y0i = (int)y0;
        const int y1i = min(y0i + 1, V - 1);
        if (PAIRED) {
            const float2 t  = s2b[y0i * D + x0i];
            const float2 u2 = s2b[y1i * D + x0i];
            bl00[u] = t.x;  bl01[u] = t.y;
            bl10[u] = u2.x; bl11[u] = u2.y;
        } else {
            const int x1i = min(x0i + 1, D - 1);
            bl00[u] = sg[y0i * D + x0i]; bl01[u] = sg[y0i * D + x1i];
            bl10[u] = sg[y1i * D + x0i]; bl11[u] = sg[y1i * D + x1i];
        }
    }

    __builtin_amdgcn_sched_barrier(0);

    float acc = 0.f;
    #pragma unroll
    for (int u = 0; u < 4; ++u) {
        const float v0f = decode_rec(ra[u][0], (unsigned short)(rz[u][0] & 0xffffu), rel[u][0]);
        const float v1f = decode_rec(ra[u][1], (unsigned short)(rz[u][1] & 0xffffu), rel[u][1]);
        const float l0 = fabsf(rel[u][0]) + 1e-4f;
        const float l1 = fabsf(rel[u][1]) + 1e-4f;
        const float recon = (v0f * l1 + v1f * l0) / (l0 + l1);
        const float wx = wxv[u], wy = wyv[u];
        const float bp = bl00[u] * (1.f - wx) * (1.f - wy) + bl01[u] * wx * (1.f - wy)
                       + bl10[u] * (1.f - wx) * wy         + bl11[u] * wx * wy;
        acc += (recon + bp) * sv[u] * 1e4f;
    }
    __builtin_nontemporal_store(acc, partial + ((size_t)chunk * B + b) * P2 + p);
}

// ---------------------------------------------------------------------------
// Kernel 3: fold the NCHUNK partials
// ---------------------------------------------------------------------------
__global__ __launch_bounds__(256) void reduce_kernel(
    const float* __restrict__ partial, float* __restrict__ out)
{
    const int i = blockIdx.x * 256 + threadIdx.x;   // 0..B*P2-1
    float a = 0.f;
    #pragma unroll 6
    for (int c = 0; c < NCHUNK; ++c)
        a += __builtin_nontemporal_load(partial + (size_t)c * B * P2 + i);
    out[i] = a;
}

// ---------------------------------------------------------------------------
extern "C" void kernel_launch(void* const* d_in, const int* in_sizes, int n_in,
                              void* d_out, int out_size, void* d_ws, size_t ws_size,
                              hipStream_t stream)
{
    const float* sinogram = (const float*)d_in[0];
    const float* feat     = (const float*)d_in[1];
    const float* grid     = (const float*)d_in[2];
    const float* sq       = (const float*)d_in[3];
    const float* w        = (const float*)d_in[4];
    const float* bias     = (const float*)d_in[5];
    float* out = (float*)d_out;

    const size_t pair_b = (size_t)B * V * PENT * PENTB;            // 47.3 MB
    const size_t part_b = (size_t)NCHUNK * B * P2 * sizeof(float); //  5.9 MB
    const size_t sg2_b  = (size_t)B * V * D * sizeof(float2);      //  5.9 MB
    const size_t rec_b  = (size_t)B * V * D * RECH * sizeof(__half); // 23.6 MB

    if (ws_size >= pair_b + part_b + sg2_b) {
        // Tier 1: pair-entry table
        char*   pair    = (char*)d_ws;
        float*  partial = (float*)((char*)d_ws + pair_b);
        float2* sg2     = (float2*)((char*)d_ws + pair_b + part_b);
        conv_kernel<1><<<dim3(720), 256, 0, stream>>>(feat, w, bias, pair);
        build_sg2<<<dim3(2880), 256, 0, stream>>>(sinogram, sg2);
        sample_pair<<<dim3(5760), 256, 0, stream>>>(pair, sg2, grid, sq, partial);
        reduce_kernel<<<dim3((B * P2) / 256), 256, 0, stream>>>(partial, out);
    } else if (ws_size >= rec_b + part_b + sg2_b) {
        // Tier 2: plain records + paired sinogram
        char*   sino    = (char*)d_ws;
        float*  partial = (float*)((char*)d_ws + rec_b);
        float2* sg2     = (float2*)((char*)d_ws + rec_b + part_b);
        conv_kernel<0><<<dim3(720), 256, 0, stream>>>(feat, w, bias, sino);
        build_sg2<<<dim3(2880), 256, 0, stream>>>(sinogram, sg2);
        sample_basic<1><<<dim3(5760), 256, 0, stream>>>((const __half*)sino, sinogram, sg2, grid, sq, partial);
        reduce_kernel<<<dim3((B * P2) / 256), 256, 0, stream>>>(partial, out);
    } else {
        // Tier 3: plain records, direct sinogram bilinear
        char*   sino    = (char*)d_ws;
        float*  partial = (float*)((char*)d_ws + rec_b);
        conv_kernel<0><<<dim3(720), 256, 0, stream>>>(feat, w, bias, sino);
        sample_basic<0><<<dim3(5760), 256, 0, stream>>>((const __half*)sino, sinogram, (const float2*)sino, grid, sq, partial);
        reduce_kernel<<<dim3((B * P2) / 256), 256, 0, stream>>>(partial, out);
    }
}

// Round 8
// 330.145 us; speedup vs baseline: 1.0357x; 1.0357x over previous
//
#include <hip/hip_runtime.h>
#include <hip/hip_fp16.h>
#include <math.h>

#define B   4
#define V   360
#define D   512
#define ENC 64
#define CH  9
#define P2  4096
#define NCHUNK 90
#define VCHUNK 4     // 360 / 90
#define RECH 16      // halfs per plain record (32 B) -- fallback layout
#define PENT 513     // pair-table entries per detector row
#define PENTB 64     // bytes per pair entry: [A ch0-7 |16| B ch0-7 |32| A8 |34| B8 |36| pad]

// ---------------------------------------------------------------------------
// Kernel 1: 3x3 conv (pad 1). 1 wave per block, 1 row per block (64 thr x
// 8 px), register double-buffered over ic, weights direct from global
// (wave-uniform -> SGPR s_load, scalar-cache resident: w = 20.7 KB).
// ---------------------------------------------------------------------------
template <int PAIR>
__global__ __launch_bounds__(64) void conv_kernel(
    const float* __restrict__ feat,   // [B,ENC,V,D]
    const float* __restrict__ w,      // [CH,ENC,3,3]
    const float* __restrict__ bias,   // [CH]
    char* __restrict__ outp)
{
    const int bid = blockIdx.x;               // 1440 = 8 * 180, bijective swizzle
    const int sw  = (bid & 7) * 180 + (bid >> 3);
    const int b   = sw / V;                   // batch b -> XCDs {2b,2b+1}
    const int v   = sw % V;
    const int d0  = threadIdx.x * 8;          // 0..504

    float acc[CH][8];
    #pragma unroll
    for (int oc = 0; oc < CH; ++oc) {
        const float bv = bias[oc];
        #pragma unroll
        for (int p = 0; p < 8; ++p) acc[oc][p] = bv;
    }

    const float* fb = feat + ((size_t)b * ENC * V + v) * D + d0;
    const bool vm = v > 0, vp = v < V - 1;
    const bool dm = d0 > 0, dp = d0 + 8 < D;

    float r0[3][10], r1[3][10];   // taps [d0-1 .. d0+8] x 3 rows

    auto ld = [&](float r[3][10], int ic) {
        const float* f = fb + (size_t)ic * (V * D);
        #pragma unroll
        for (int rr = 0; rr < 3; ++rr) {
            const float* fr = f + (rr - 1) * D;
            const bool ok = (rr == 0) ? vm : ((rr == 2) ? vp : true);
            float4 c0 = ok ? *(const float4*)fr       : float4{0.f, 0.f, 0.f, 0.f};
            float4 c1 = ok ? *(const float4*)(fr + 4) : float4{0.f, 0.f, 0.f, 0.f};
            r[rr][1] = c0.x; r[rr][2] = c0.y; r[rr][3] = c0.z; r[rr][4] = c0.w;
            r[rr][5] = c1.x; r[rr][6] = c1.y; r[rr][7] = c1.z; r[rr][8] = c1.w;
            r[rr][0] = (ok && dm) ? fr[-1] : 0.f;
            r[rr][9] = (ok && dp) ? fr[8]  : 0.f;
        }
    };
    auto fmab = [&](const float r[3][10], int ic) {
        #pragma unroll
        for (int oc = 0; oc < CH; ++oc) {
            const float* ww = w + ((size_t)oc * ENC + ic) * 9;  // SGPR loads
            #pragma unroll
            for (int kr = 0; kr < 3; ++kr) {
                #pragma unroll
                for (int kc = 0; kc < 3; ++kc) {
                    const float wv = ww[kr * 3 + kc];
                    #pragma unroll
                    for (int p = 0; p < 8; ++p)
                        acc[oc][p] = fmaf(r[kr][p + kc], wv, acc[oc][p]);
                }
            }
        }
    };

    ld(r0, 0);
    #pragma unroll 1
    for (int ic = 0; ic < ENC; ic += 2) {
        ld(r1, ic + 1);                 // prefetch next ic while computing
        fmab(r0, ic);
        if (ic + 2 < ENC) ld(r0, ic + 2);
        fmab(r1, ic + 1);
    }

    #pragma unroll
    for (int p = 0; p < 8; ++p) {
        union { __half2 h; unsigned u; } cv;
        uint4 pk;
        cv.h = __floats2half2_rn(acc[0][p], acc[1][p]); pk.x = cv.u;
        cv.h = __floats2half2_rn(acc[2][p], acc[3][p]); pk.y = cv.u;
        cv.h = __floats2half2_rn(acc[4][p], acc[5][p]); pk.z = cv.u;
        cv.h = __floats2half2_rn(acc[6][p], acc[7][p]); pk.w = cv.u;
        cv.h = __floats2half2_rn(acc[8][p], 0.f);
        const unsigned short z = (unsigned short)(cv.u & 0xffffu);
        const int x = d0 + p;
        if (PAIR) {
            char* row = outp + (size_t)(b * V + v) * PENT * PENTB;
            char* eA = row + (size_t)(x + 1) * PENTB;       // A-half of entry x+1
            *(uint4*)eA = pk;
            *(unsigned short*)(eA + 32) = z;
            char* eB = row + (size_t)x * PENTB + 16;        // B-half of entry x
            *(uint4*)eB = pk;
            *(unsigned short*)(eB + 18) = z;                // byte 34 of entry
            if (x == 0) {                                   // entry 0: A = rec[0]
                *(uint4*)row = pk;
                *(unsigned short*)(row + 32) = z;
            }
            if (x == D - 1) {                               // entry 512: B = rec[511]
                char* eC = row + (size_t)512 * PENTB + 16;
                *(uint4*)eC = pk;
                *(unsigned short*)(eC + 18) = z;
            }
        } else {
            __half* rec = (__half*)outp + (size_t)(((size_t)b * V + v) * D + x) * RECH;
            *(uint4*)rec = pk;
            *(unsigned*)(rec + 8) = (unsigned)z;
        }
    }
}

// ---------------------------------------------------------------------------
// Kernel 1b: 4-tap sinogram table
// sg4[b,v,x] = (s[v][x], s[v][x+1], s[v+1][x], s[v+1][x+1]) (clamped)
// ---------------------------------------------------------------------------
__global__ __launch_bounds__(256) void build_sg4(
    const float* __restrict__ sg, float4* __restrict__ sg4)
{
    const int i  = blockIdx.x * 256 + threadIdx.x;  // B*V*D = 737280 = 2880*256
    const int x  = i & (D - 1);
    const int bv = i >> 9;
    const int v  = bv % V;
    const float a = sg[i];
    const float c = (x < D - 1) ? sg[i + 1] : a;
    const int i2 = (v < V - 1) ? i + D : i;
    const float d2 = sg[i2];
    const float e2 = (x < D - 1) ? sg[i2 + 1] : d2;
    sg4[i] = float4{a, c, d2, e2};
}

// ---------------------------------------------------------------------------
// Kernel 1c: paired sinogram table (tier-2 fallback)
// ---------------------------------------------------------------------------
__global__ __launch_bounds__(256) void build_sg2(
    const float* __restrict__ sg, float2* __restrict__ sg2)
{
    const int i = blockIdx.x * 256 + threadIdx.x;
    const int x = i & (D - 1);
    const float a = sg[i];
    const float c = (x == D - 1) ? a : sg[i + 1];
    sg2[i] = float2{a, c};
}

// ---------------------------------------------------------------------------
// Shared math: Fourier decode of one record
// ---------------------------------------------------------------------------
__device__ __forceinline__ float decode_rec(uint4 a, unsigned short z, float rel)
{
    float q[9];
    union { unsigned uu; __half2 h; } c;
    float2 f;
    c.uu = a.x; f = __half22float2(c.h); q[0] = f.x; q[1] = f.y;
    c.uu = a.y; f = __half22float2(c.h); q[2] = f.x; q[3] = f.y;
    c.uu = a.z; f = __half22float2(c.h); q[4] = f.x; q[5] = f.y;
    c.uu = a.w; f = __half22float2(c.h); q[6] = f.x; q[7] = f.y;
    union { unsigned short us; __half hh; } c2;
    c2.us = z;
    q[8] = __half2float(c2.hh);

    const float ang = rel * 1.5707963267948966f;  // OMEGA
    float s1, c1;
    __sincosf(ang, &s1, &c1);
    const float c2f = fmaf(2.f * c1, c1, -1.f);
    const float s2f = 2.f * c1 * s1;
    const float c3f = fmaf(2.f * c1, c2f, -c1);
    const float s3f = fmaf(2.f * c1, s2f, -s1);
    const float c4f = fmaf(2.f * c1, c3f, -c2f);
    const float s4f = fmaf(2.f * c1, s3f, -s2f);

    float vv = q[0];
    vv = fmaf(q[1], c1,  vv); vv = fmaf(q[2], c2f, vv);
    vv = fmaf(q[3], c3f, vv); vv = fmaf(q[4], c4f, vv);
    vv = fmaf(q[5], s1,  vv); vv = fmaf(q[6], s2f, vv);
    vv = fmaf(q[7], s3f, vv); vv = fmaf(q[8], s4f, vv);
    return vv;
}

// ---------------------------------------------------------------------------
// Kernel 2 (pair path): 4 scattered loads/point (qa, zAB dword, qb, sg4).
// ---------------------------------------------------------------------------
template <int SG4>
__global__ __launch_bounds__(256) void sample_pair(
    const char* __restrict__ pair,       // [B,V,PENT,64B]
    const float4* __restrict__ sg4,      // [B,V,D] 4-tap table
    const float2* __restrict__ sg2,      // [B,V,D] paired (tier-2)
    const float* __restrict__ grid,      // [B,V,P2,2]
    const float* __restrict__ sq,        // [B,1,V,P2]
    float* __restrict__ partial)         // [NCHUNK,B,P2]
{
    const int bid = blockIdx.x;          // 5760 = 8 XCDs * 720
    const int xcd = bid & 7;
    const int b   = xcd >> 1;            // batch b owned by XCDs {2b,2b+1}
    const int idx = ((bid >> 3) << 1) | (xcd & 1);  // 0..1439
    const int chunk = idx >> 4;                     // 0..89
    const int p  = (idx & 15) * 256 + threadIdx.x;
    const int v0 = chunk * VCHUNK;

    const char*   pb  = pair + (size_t)b * V * PENT * PENTB;
    const float4* s4b = sg4 + (size_t)b * V * D;
    const float2* s2b = sg2 + (size_t)b * V * D;

    // ---- phase A: coalesced streaming loads --------------------------------
    float gx[4], gy[4], sv[4];
    #pragma unroll
    for (int u = 0; u < 4; ++u) {
        const size_t gi = (size_t)(b * V + v0 + u) * P2 + p;
        const double gd = __builtin_nontemporal_load((const double*)grid + gi);
        const unsigned long long gu = __double_as_longlong(gd);
        gx[u] = __uint_as_float((unsigned)gu);
        gy[u] = __uint_as_float((unsigned)(gu >> 32));
        sv[u] = __builtin_nontemporal_load(sq + gi);
    }

    // ---- phase B: pair-entry gathers ---------------------------------------
    uint4 qa[4], qb[4];
    unsigned short zA[4], zB[4];
    float relm[4], relp[4];
    #pragma unroll
    for (int u = 0; u < 4; ++u) {
        const float fy = ((gy[u] + 1e-6f + 1.f) * (float)V - 1.f) * 0.5f;
        const int   yi = (int)fminf(fmaxf(rintf(fy), 0.f), (float)(V - 1));
        const float fx0 = ((gx[u] + 1e-6f + 1.f) * (float)D - 1.f) * 0.5f;
        const int xm = (int)fminf(fmaxf(rintf(fx0 - 0.5f), 0.f), (float)(D - 1));
        const int xp = (int)fminf(fmaxf(rintf(fx0 + 0.5f), 0.f), (float)(D - 1));
        const float qcm = ((float)xm + 0.5f) * (2.f / (float)D) - 1.f;
        const float qcp = ((float)xp + 0.5f) * (2.f / (float)D) - 1.f;
        relm[u] = (gx[u] - qcm) * (float)D;
        relp[u] = (gx[u] - qcp) * (float)D;
        const char* rowp = pb + (size_t)yi * (PENT * PENTB);
        const char* e1 = rowp + (size_t)(xm + 1) * PENTB;   // A-half = rec[xm]
        const char* e2 = rowp + (size_t)xp * PENTB;         // B-half = rec[xp]
        qa[u] = *(const uint4*)e1;
        qb[u] = *(const uint4*)(e2 + 16);
        const unsigned zab = *(const unsigned*)(e1 + 32);   // A8|B8 of entry e1
        zA[u] = (unsigned short)(zab & 0xffffu);
        // common case xp == xm+1  =>  e2 == e1: B8 is the high half.
        zB[u] = (e2 == e1) ? (unsigned short)(zab >> 16)
                           : *(const unsigned short*)(e2 + 34);
    }

    // ---- phase C: bilinear gathers -----------------------------------------
    float bl00[4], bl01[4], bl10[4], bl11[4], wxv[4], wyv[4];
    #pragma unroll
    for (int u = 0; u < 4; ++u) {
        float fxb = fminf(fmaxf(((gx[u] + 1.f) * (float)D - 1.f) * 0.5f, 0.f), (float)(D - 1));
        float fyb = fminf(fmaxf(((gy[u] + 1.f) * (float)V - 1.f) * 0.5f, 0.f), (float)(V - 1));
        const float x0 = floorf(fxb), y0 = floorf(fyb);
        wxv[u] = fxb - x0; wyv[u] = fyb - y0;
        const int x0i = (int)x0, y0i = (int)y0;
        if (SG4) {
            const float4 t = s4b[y0i * D + x0i];
            bl00[u] = t.x; bl01[u] = t.y; bl10[u] = t.z; bl11[u] = t.w;
        } else {
            const int y1i = min(y0i + 1, V - 1);
            const float2 t  = s2b[y0i * D + x0i];
            const float2 u2 = s2b[y1i * D + x0i];
            bl00[u] = t.x;  bl01[u] = t.y;
            bl10[u] = u2.x; bl11[u] = u2.y;
        }
    }

    // Keep every gather above in flight before any math below.
    __builtin_amdgcn_sched_barrier(0);

    // ---- phase D: math ------------------------------------------------------
    float acc = 0.f;
    #pragma unroll
    for (int u = 0; u < 4; ++u) {
        const float vmv = decode_rec(qa[u], zA[u], relm[u]);
        const float vpv = decode_rec(qb[u], zB[u], relp[u]);
        const float lm = fabsf(relm[u]) + 1e-4f;
        const float lp = fabsf(relp[u]) + 1e-4f;
        const float recon = (vmv * lp + vpv * lm) / (lm + lp);

        const float wx = wxv[u], wy = wyv[u];
        const float bp = bl00[u] * (1.f - wx) * (1.f - wy) + bl01[u] * wx * (1.f - wy)
                       + bl10[u] * (1.f - wx) * wy         + bl11[u] * wx * wy;

        acc += (recon + bp) * sv[u] * 1e4f;
    }
    __builtin_nontemporal_store(acc, partial + ((size_t)chunk * B + b) * P2 + p);
}

// ---------------------------------------------------------------------------
// Kernel 2 fallback: plain 32B records
// ---------------------------------------------------------------------------
template <int PAIRED>
__global__ __launch_bounds__(256) void sample_basic(
    const __half* __restrict__ sino,     // [B,V,D,RECH]
    const float* __restrict__ sinogram,  // [B,1,V,D]
    const float2* __restrict__ sg2,      // [B,V,D] paired
    const float* __restrict__ grid,
    const float* __restrict__ sq,
    float* __restrict__ partial)
{
    const int bid = blockIdx.x;
    const int xcd = bid & 7;
    const int b   = xcd >> 1;
    const int idx = ((bid >> 3) << 1) | (xcd & 1);
    const int chunk = idx >> 4;
    const int p  = (idx & 15) * 256 + threadIdx.x;
    const int v0 = chunk * VCHUNK;

    const float*  sg   = sinogram + (size_t)b * V * D;
    const float2* s2b  = sg2 + (size_t)b * V * D;
    const __half* sb   = sino + (size_t)b * V * D * RECH;

    float gx[4], gy[4], sv[4];
    #pragma unroll
    for (int u = 0; u < 4; ++u) {
        const size_t gi = (size_t)(b * V + v0 + u) * P2 + p;
        const double gd = __builtin_nontemporal_load((const double*)grid + gi);
        const unsigned long long gu = __double_as_longlong(gd);
        gx[u] = __uint_as_float((unsigned)gu);
        gy[u] = __uint_as_float((unsigned)(gu >> 32));
        sv[u] = __builtin_nontemporal_load(sq + gi);
    }

    uint4    ra[4][2];
    unsigned rz[4][2];
    float    rel[4][2];
    #pragma unroll
    for (int u = 0; u < 4; ++u) {
        const float fy = ((gy[u] + 1e-6f + 1.f) * (float)V - 1.f) * 0.5f;
        const int   yi = (int)fminf(fmaxf(rintf(fy), 0.f), (float)(V - 1));
        const float fx0 = ((gx[u] + 1e-6f + 1.f) * (float)D - 1.f) * 0.5f;
        #pragma unroll
        for (int sft = 0; sft < 2; ++sft) {
            const float fx = (sft == 0) ? (fx0 - 0.5f) : (fx0 + 0.5f);
            const int   xi = (int)fminf(fmaxf(rintf(fx), 0.f), (float)(D - 1));
            const float qc = ((float)xi + 0.5f) * (2.f / (float)D) - 1.f;
            rel[u][sft] = (gx[u] - qc) * (float)D;
            const __half* rec = sb + (size_t)(yi * D + xi) * RECH;
            ra[u][sft] = *(const uint4*)rec;
            rz[u][sft] = *(const unsigned*)(rec + 8);
        }
    }

    float bl00[4], bl01[4], bl10[4], bl11[4], wxv[4], wyv[4];
    #pragma unroll
    for (int u = 0; u < 4; ++u) {
        float fxb = fminf(fmaxf(((gx[u] + 1.f) * (float)D - 1.f) * 0.5f, 0.f), (float)(D - 1));
        float fyb = fminf(fmaxf(((gy[u] + 1.f) * (float)V - 1.f) * 0.5f, 0.f), (float)(V - 1));
        const float x0 = floorf(fxb), y0 = floorf(fyb);
        wxv[u] = fxb - x0; wyv[u] = fyb - y0;
        const int x0i = (int)x0, y0i = (int)y0;
        const int y1i = min(y0i + 1, V - 1);
        if (PAIRED) {
            const float2 t  = s2b[y0i * D + x0i];
            const float2 u2 = s2b[y1i * D + x0i];
            bl00[u] = t.x;  bl01[u] = t.y;
            bl10[u] = u2.x; bl11[u] = u2.y;
        } else {
            const int x1i = min(x0i + 1, D - 1);
            bl00[u] = sg[y0i * D + x0i]; bl01[u] = sg[y0i * D + x1i];
            bl10[u] = sg[y1i * D + x0i]; bl11[u] = sg[y1i * D + x1i];
        }
    }

    __builtin_amdgcn_sched_barrier(0);

    float acc = 0.f;
    #pragma unroll
    for (int u = 0; u < 4; ++u) {
        const float v0f = decode_rec(ra[u][0], (unsigned short)(rz[u][0] & 0xffffu), rel[u][0]);
        const float v1f = decode_rec(ra[u][1], (unsigned short)(rz[u][1] & 0xffffu), rel[u][1]);
        const float l0 = fabsf(rel[u][0]) + 1e-4f;
        const float l1 = fabsf(rel[u][1]) + 1e-4f;
        const float recon = (v0f * l1 + v1f * l0) / (l0 + l1);
        const float wx = wxv[u], wy = wyv[u];
        const float bp = bl00[u] * (1.f - wx) * (1.f - wy) + bl01[u] * wx * (1.f - wy)
                       + bl10[u] * (1.f - wx) * wy         + bl11[u] * wx * wy;
        acc += (recon + bp) * sv[u] * 1e4f;
    }
    __builtin_nontemporal_store(acc, partial + ((size_t)chunk * B + b) * P2 + p);
}

// ---------------------------------------------------------------------------
// Kernel 3: fold the NCHUNK partials
// ---------------------------------------------------------------------------
__global__ __launch_bounds__(256) void reduce_kernel(
    const float* __restrict__ partial, float* __restrict__ out)
{
    const int i = blockIdx.x * 256 + threadIdx.x;   // 0..B*P2-1
    float a = 0.f;
    #pragma unroll 6
    for (int c = 0; c < NCHUNK; ++c)
        a += __builtin_nontemporal_load(partial + (size_t)c * B * P2 + i);
    out[i] = a;
}

// ---------------------------------------------------------------------------
extern "C" void kernel_launch(void* const* d_in, const int* in_sizes, int n_in,
                              void* d_out, int out_size, void* d_ws, size_t ws_size,
                              hipStream_t stream)
{
    const float* sinogram = (const float*)d_in[0];
    const float* feat     = (const float*)d_in[1];
    const float* grid     = (const float*)d_in[2];
    const float* sq       = (const float*)d_in[3];
    const float* w        = (const float*)d_in[4];
    const float* bias     = (const float*)d_in[5];
    float* out = (float*)d_out;

    const size_t pair_b = (size_t)B * V * PENT * PENTB;              // 47.3 MB
    const size_t part_b = (size_t)NCHUNK * B * P2 * sizeof(float);   //  5.9 MB
    const size_t sg4_b  = (size_t)B * V * D * sizeof(float4);        // 11.8 MB
    const size_t sg2_b  = (size_t)B * V * D * sizeof(float2);        //  5.9 MB
    const size_t rec_b  = (size_t)B * V * D * RECH * sizeof(__half); // 23.6 MB

    if (ws_size >= pair_b + part_b + sg4_b) {
        // Tier 1: pair-entry table + 4-tap sinogram table
        char*   pair    = (char*)d_ws;
        float*  partial = (float*)((char*)d_ws + pair_b);
        float4* sg4     = (float4*)((char*)d_ws + pair_b + part_b);
        conv_kernel<1><<<dim3(1440), 64, 0, stream>>>(feat, w, bias, pair);
        build_sg4<<<dim3(2880), 256, 0, stream>>>(sinogram, sg4);
        sample_pair<1><<<dim3(5760), 256, 0, stream>>>(pair, sg4, (const float2*)sg4, grid, sq, partial);
        reduce_kernel<<<dim3((B * P2) / 256), 256, 0, stream>>>(partial, out);
    } else if (ws_size >= pair_b + part_b + sg2_b) {
        // Tier 2: pair-entry table + 2-tap sinogram table
        char*   pair    = (char*)d_ws;
        float*  partial = (float*)((char*)d_ws + pair_b);
        float2* sg2     = (float2*)((char*)d_ws + pair_b + part_b);
        conv_kernel<1><<<dim3(1440), 64, 0, stream>>>(feat, w, bias, pair);
        build_sg2<<<dim3(2880), 256, 0, stream>>>(sinogram, sg2);
        sample_pair<0><<<dim3(5760), 256, 0, stream>>>(pair, (const float4*)sg2, sg2, grid, sq, partial);
        reduce_kernel<<<dim3((B * P2) / 256), 256, 0, stream>>>(partial, out);
    } else if (ws_size >= rec_b + part_b + sg2_b) {
        // Tier 3: plain records + paired sinogram
        char*   sino    = (char*)d_ws;
        float*  partial = (float*)((char*)d_ws + rec_b);
        float2* sg2     = (float2*)((char*)d_ws + rec_b + part_b);
        conv_kernel<0><<<dim3(1440), 64, 0, stream>>>(feat, w, bias, sino);
        build_sg2<<<dim3(2880), 256, 0, stream>>>(sinogram, sg2);
        sample_basic<1><<<dim3(5760), 256, 0, stream>>>((const __half*)sino, sinogram, sg2, grid, sq, partial);
        reduce_kernel<<<dim3((B * P2) / 256), 256, 0, stream>>>(partial, out);
    } else {
        // Tier 4: plain records, direct sinogram bilinear
        char*   sino    = (char*)d_ws;
        float*  partial = (float*)((char*)d_ws + rec_b);
        conv_kernel<0><<<dim3(1440), 64, 0, stream>>>(feat, w, bias, sino);
        sample_basic<0><<<dim3(5760), 256, 0, stream>>>((const __half*)sino, sinogram, (const float2*)sino, grid, sq, partial);
        reduce_kernel<<<dim3((B * P2) / 256), 256, 0, stream>>>(partial, out);
    }
}

// Round 9
// 288.687 us; speedup vs baseline: 1.1844x; 1.1436x over previous
//
#include <hip/hip_runtime.h>
#include <hip/hip_fp16.h>
#include <math.h>

#define B   4
#define V   360
#define D   512
#define ENC 64
#define CH  9
#define P2  4096
#define NCHUNK 90
#define VCHUNK 4     // 360 / 90
#define RECH 16      // halfs per plain record (32 B) -- fallback layout
#define PENT 513     // pair-table entries per detector row
#define PENTB 64     // bytes per pair entry: [A ch0-7 |16| B ch0-7 |32| A8 |34| B8 |36| pad]

// ---------------------------------------------------------------------------
// Kernel 1: 3x3 conv (pad 1). R4's measured-best shape (720 blocks, 256 thr,
// 2 rows x 128 thr x 4 px, SGPR weights) + register double-buffer over ic.
// ---------------------------------------------------------------------------
template <int PAIR>
__global__ __launch_bounds__(256) void conv_kernel(
    const float* __restrict__ feat,   // [B,ENC,V,D]
    const float* __restrict__ w,      // [CH,ENC,3,3]
    const float* __restrict__ bias,   // [CH]
    char* __restrict__ outp)
{
    const int bid = blockIdx.x;               // 720 = 8 * 90, bijective swizzle
    const int sw  = (bid & 7) * 90 + (bid >> 3);
    const int b   = sw / 180;                 // batch b -> XCDs {2b,2b+1}
    const int vt  = sw % 180;
    const int tr  = threadIdx.x >> 7;         // row within tile: 0..1
    const int v   = vt * 2 + tr;
    const int d0  = (threadIdx.x & 127) * 4;  // 0..508

    float acc[CH][4];
    #pragma unroll
    for (int oc = 0; oc < CH; ++oc) {
        const float bv = bias[oc];
        #pragma unroll
        for (int p = 0; p < 4; ++p) acc[oc][p] = bv;
    }

    const float* fb = feat + ((size_t)b * ENC * V + v) * D + d0;
    const bool vm = v > 0, vp = v < V - 1;
    const bool dm = d0 > 0, dp = d0 + 4 < D;

    float r0[3][6], r1[3][6];   // taps [d0-1 .. d0+4] x 3 rows

    auto ld = [&](float r[3][6], int ic) {
        const float* f = fb + (size_t)ic * (V * D);
        #pragma unroll
        for (int rr = 0; rr < 3; ++rr) {
            const float* fr = f + (rr - 1) * D;
            const bool ok = (rr == 0) ? vm : ((rr == 2) ? vp : true);
            float4 c = ok ? *(const float4*)fr : float4{0.f, 0.f, 0.f, 0.f};
            r[rr][1] = c.x; r[rr][2] = c.y; r[rr][3] = c.z; r[rr][4] = c.w;
            r[rr][0] = (ok && dm) ? fr[-1] : 0.f;
            r[rr][5] = (ok && dp) ? fr[4]  : 0.f;
        }
    };
    auto fmab = [&](const float r[3][6], int ic) {
        #pragma unroll
        for (int oc = 0; oc < CH; ++oc) {
            const float* ww = w + ((size_t)oc * ENC + ic) * 9;  // SGPR loads
            #pragma unroll
            for (int kr = 0; kr < 3; ++kr) {
                #pragma unroll
                for (int kc = 0; kc < 3; ++kc) {
                    const float wv = ww[kr * 3 + kc];
                    #pragma unroll
                    for (int p = 0; p < 4; ++p)
                        acc[oc][p] = fmaf(r[kr][p + kc], wv, acc[oc][p]);
                }
            }
        }
    };

    ld(r0, 0);
    #pragma unroll 1
    for (int ic = 0; ic < ENC; ic += 2) {
        ld(r1, ic + 1);                 // prefetch next ic while computing
        fmab(r0, ic);
        if (ic + 2 < ENC) ld(r0, ic + 2);
        fmab(r1, ic + 1);
    }

    #pragma unroll
    for (int p = 0; p < 4; ++p) {
        union { __half2 h; unsigned u; } cv;
        uint4 pk;
        cv.h = __floats2half2_rn(acc[0][p], acc[1][p]); pk.x = cv.u;
        cv.h = __floats2half2_rn(acc[2][p], acc[3][p]); pk.y = cv.u;
        cv.h = __floats2half2_rn(acc[4][p], acc[5][p]); pk.z = cv.u;
        cv.h = __floats2half2_rn(acc[6][p], acc[7][p]); pk.w = cv.u;
        cv.h = __floats2half2_rn(acc[8][p], 0.f);
        const unsigned short z = (unsigned short)(cv.u & 0xffffu);
        const int x = d0 + p;
        if (PAIR) {
            char* row = outp + (size_t)(b * V + v) * PENT * PENTB;
            char* eA = row + (size_t)(x + 1) * PENTB;       // A-half of entry x+1
            *(uint4*)eA = pk;
            *(unsigned short*)(eA + 32) = z;
            char* eB = row + (size_t)x * PENTB + 16;        // B-half of entry x
            *(uint4*)eB = pk;
            *(unsigned short*)(eB + 18) = z;                // byte 34 of entry
            if (x == 0) {                                   // entry 0: A = rec[0]
                *(uint4*)row = pk;
                *(unsigned short*)(row + 32) = z;
            }
            if (x == D - 1) {                               // entry 512: B = rec[511]
                char* eC = row + (size_t)512 * PENTB + 16;
                *(uint4*)eC = pk;
                *(unsigned short*)(eC + 18) = z;
            }
        } else {
            __half* rec = (__half*)outp + (size_t)(((size_t)b * V + v) * D + x) * RECH;
            *(uint4*)rec = pk;
            *(unsigned*)(rec + 8) = (unsigned)z;
        }
    }
}

// ---------------------------------------------------------------------------
// Kernel 1b: 4-tap sinogram table
// sg4[b,v,x] = (s[v][x], s[v][x+1], s[v+1][x], s[v+1][x+1]) (clamped)
// ---------------------------------------------------------------------------
__global__ __launch_bounds__(256) void build_sg4(
    const float* __restrict__ sg, float4* __restrict__ sg4)
{
    const int i  = blockIdx.x * 256 + threadIdx.x;  // B*V*D = 737280 = 2880*256
    const int x  = i & (D - 1);
    const int bv = i >> 9;
    const int v  = bv % V;
    const float a = sg[i];
    const float c = (x < D - 1) ? sg[i + 1] : a;
    const int i2 = (v < V - 1) ? i + D : i;
    const float d2 = sg[i2];
    const float e2 = (x < D - 1) ? sg[i2 + 1] : d2;
    sg4[i] = float4{a, c, d2, e2};
}

// ---------------------------------------------------------------------------
// Kernel 1c: paired sinogram table (fallback)
// ---------------------------------------------------------------------------
__global__ __launch_bounds__(256) void build_sg2(
    const float* __restrict__ sg, float2* __restrict__ sg2)
{
    const int i = blockIdx.x * 256 + threadIdx.x;
    const int x = i & (D - 1);
    const float a = sg[i];
    const float c = (x == D - 1) ? a : sg[i + 1];
    sg2[i] = float2{a, c};
}

// ---------------------------------------------------------------------------
// Shared math: Fourier decode of one record
// ---------------------------------------------------------------------------
__device__ __forceinline__ float decode_rec(uint4 a, unsigned short z, float rel)
{
    float q[9];
    union { unsigned uu; __half2 h; } c;
    float2 f;
    c.uu = a.x; f = __half22float2(c.h); q[0] = f.x; q[1] = f.y;
    c.uu = a.y; f = __half22float2(c.h); q[2] = f.x; q[3] = f.y;
    c.uu = a.z; f = __half22float2(c.h); q[4] = f.x; q[5] = f.y;
    c.uu = a.w; f = __half22float2(c.h); q[6] = f.x; q[7] = f.y;
    union { unsigned short us; __half hh; } c2;
    c2.us = z;
    q[8] = __half2float(c2.hh);

    const float ang = rel * 1.5707963267948966f;  // OMEGA
    float s1, c1;
    __sincosf(ang, &s1, &c1);
    const float c2f = fmaf(2.f * c1, c1, -1.f);
    const float s2f = 2.f * c1 * s1;
    const float c3f = fmaf(2.f * c1, c2f, -c1);
    const float s3f = fmaf(2.f * c1, s2f, -s1);
    const float c4f = fmaf(2.f * c1, c3f, -c2f);
    const float s4f = fmaf(2.f * c1, s3f, -s2f);

    float vv = q[0];
    vv = fmaf(q[1], c1,  vv); vv = fmaf(q[2], c2f, vv);
    vv = fmaf(q[3], c3f, vv); vv = fmaf(q[4], c4f, vv);
    vv = fmaf(q[5], s1,  vv); vv = fmaf(q[6], s2f, vv);
    vv = fmaf(q[7], s3f, vv); vv = fmaf(q[8], s4f, vv);
    return vv;
}

// ---------------------------------------------------------------------------
// Kernel 2 (pair path): 4 scattered loads/point (qa, qb, zAB dword, sg4).
// ---------------------------------------------------------------------------
template <int SG4>
__global__ __launch_bounds__(256) void sample_pair(
    const char* __restrict__ pair,       // [B,V,PENT,64B]
    const float4* __restrict__ sg4,      // [B,V,D] 4-tap table
    const float2* __restrict__ sg2,      // [B,V,D] paired (tier-2)
    const float* __restrict__ grid,      // [B,V,P2,2]
    const float* __restrict__ sq,        // [B,1,V,P2]
    float* __restrict__ partial)         // [NCHUNK,B,P2]
{
    const int bid = blockIdx.x;          // 5760 = 8 XCDs * 720
    const int xcd = bid & 7;
    const int b   = xcd >> 1;            // batch b owned by XCDs {2b,2b+1}
    const int idx = ((bid >> 3) << 1) | (xcd & 1);  // 0..1439
    const int chunk = idx >> 4;                     // 0..89
    const int p  = (idx & 15) * 256 + threadIdx.x;
    const int v0 = chunk * VCHUNK;

    const char*   pb  = pair + (size_t)b * V * PENT * PENTB;
    const float4* s4b = sg4 + (size_t)b * V * D;
    const float2* s2b = sg2 + (size_t)b * V * D;

    // ---- phase A: coalesced streaming loads --------------------------------
    float gx[4], gy[4], sv[4];
    #pragma unroll
    for (int u = 0; u < 4; ++u) {
        const size_t gi = (size_t)(b * V + v0 + u) * P2 + p;
        const double gd = __builtin_nontemporal_load((const double*)grid + gi);
        const unsigned long long gu = __double_as_longlong(gd);
        gx[u] = __uint_as_float((unsigned)gu);
        gy[u] = __uint_as_float((unsigned)(gu >> 32));
        sv[u] = __builtin_nontemporal_load(sq + gi);
    }

    // ---- phase B: pair-entry gathers ---------------------------------------
    uint4 qa[4], qb[4];
    unsigned short zA[4], zB[4];
    float relm[4], relp[4];
    #pragma unroll
    for (int u = 0; u < 4; ++u) {
        const float fy = ((gy[u] + 1e-6f + 1.f) * (float)V - 1.f) * 0.5f;
        const int   yi = (int)fminf(fmaxf(rintf(fy), 0.f), (float)(V - 1));
        const float fx0 = ((gx[u] + 1e-6f + 1.f) * (float)D - 1.f) * 0.5f;
        const int xm = (int)fminf(fmaxf(rintf(fx0 - 0.5f), 0.f), (float)(D - 1));
        const int xp = (int)fminf(fmaxf(rintf(fx0 + 0.5f), 0.f), (float)(D - 1));
        const float qcm = ((float)xm + 0.5f) * (2.f / (float)D) - 1.f;
        const float qcp = ((float)xp + 0.5f) * (2.f / (float)D) - 1.f;
        relm[u] = (gx[u] - qcm) * (float)D;
        relp[u] = (gx[u] - qcp) * (float)D;
        const char* rowp = pb + (size_t)yi * (PENT * PENTB);
        const char* e1 = rowp + (size_t)(xm + 1) * PENTB;   // A-half = rec[xm]
        const char* e2 = rowp + (size_t)xp * PENTB;         // B-half = rec[xp]
        qa[u] = *(const uint4*)e1;
        qb[u] = *(const uint4*)(e2 + 16);
        const unsigned zab = *(const unsigned*)(e1 + 32);   // A8|B8 of entry e1
        zA[u] = (unsigned short)(zab & 0xffffu);
        // common case xp == xm+1  =>  e2 == e1: B8 is the high half.
        zB[u] = (e2 == e1) ? (unsigned short)(zab >> 16)
                           : *(const unsigned short*)(e2 + 34);
    }

    // ---- phase C: bilinear gathers -----------------------------------------
    float bl00[4], bl01[4], bl10[4], bl11[4], wxv[4], wyv[4];
    #pragma unroll
    for (int u = 0; u < 4; ++u) {
        float fxb = fminf(fmaxf(((gx[u] + 1.f) * (float)D - 1.f) * 0.5f, 0.f), (float)(D - 1));
        float fyb = fminf(fmaxf(((gy[u] + 1.f) * (float)V - 1.f) * 0.5f, 0.f), (float)(V - 1));
        const float x0 = floorf(fxb), y0 = floorf(fyb);
        wxv[u] = fxb - x0; wyv[u] = fyb - y0;
        const int x0i = (int)x0, y0i = (int)y0;
        if (SG4) {
            const float4 t = s4b[y0i * D + x0i];
            bl00[u] = t.x; bl01[u] = t.y; bl10[u] = t.z; bl11[u] = t.w;
        } else {
            const int y1i = min(y0i + 1, V - 1);
            const float2 t  = s2b[y0i * D + x0i];
            const float2 u2 = s2b[y1i * D + x0i];
            bl00[u] = t.x;  bl01[u] = t.y;
            bl10[u] = u2.x; bl11[u] = u2.y;
        }
    }

    // Keep every gather above in flight before any math below.
    __builtin_amdgcn_sched_barrier(0);

    // ---- phase D: math ------------------------------------------------------
    float acc = 0.f;
    #pragma unroll
    for (int u = 0; u < 4; ++u) {
        const float vmv = decode_rec(qa[u], zA[u], relm[u]);
        const float vpv = decode_rec(qb[u], zB[u], relp[u]);
        const float lm = fabsf(relm[u]) + 1e-4f;
        const float lp = fabsf(relp[u]) + 1e-4f;
        const float recon = (vmv * lp + vpv * lm) / (lm + lp);

        const float wx = wxv[u], wy = wyv[u];
        const float bp = bl00[u] * (1.f - wx) * (1.f - wy) + bl01[u] * wx * (1.f - wy)
                       + bl10[u] * (1.f - wx) * wy         + bl11[u] * wx * wy;

        acc += (recon + bp) * sv[u] * 1e4f;
    }
    __builtin_nontemporal_store(acc, partial + ((size_t)chunk * B + b) * P2 + p);
}

// ---------------------------------------------------------------------------
// Kernel 2 fallback: plain 32B records
// ---------------------------------------------------------------------------
template <int PAIRED>
__global__ __launch_bounds__(256) void sample_basic(
    const __half* __restrict__ sino,     // [B,V,D,RECH]
    const float* __restrict__ sinogram,  // [B,1,V,D]
    const float2* __restrict__ sg2,      // [B,V,D] paired
    const float* __restrict__ grid,
    const float* __restrict__ sq,
    float* __restrict__ partial)
{
    const int bid = blockIdx.x;
    const int xcd = bid & 7;
    const int b   = xcd >> 1;
    const int idx = ((bid >> 3) << 1) | (xcd & 1);
    const int chunk = idx >> 4;
    const int p  = (idx & 15) * 256 + threadIdx.x;
    const int v0 = chunk * VCHUNK;

    const float*  sg   = sinogram + (size_t)b * V * D;
    const float2* s2b  = sg2 + (size_t)b * V * D;
    const __half* sb   = sino + (size_t)b * V * D * RECH;

    float gx[4], gy[4], sv[4];
    #pragma unroll
    for (int u = 0; u < 4; ++u) {
        const size_t gi = (size_t)(b * V + v0 + u) * P2 + p;
        const double gd = __builtin_nontemporal_load((const double*)grid + gi);
        const unsigned long long gu = __double_as_longlong(gd);
        gx[u] = __uint_as_float((unsigned)gu);
        gy[u] = __uint_as_float((unsigned)(gu >> 32));
        sv[u] = __builtin_nontemporal_load(sq + gi);
    }

    uint4    ra[4][2];
    unsigned rz[4][2];
    float    rel[4][2];
    #pragma unroll
    for (int u = 0; u < 4; ++u) {
        const float fy = ((gy[u] + 1e-6f + 1.f) * (float)V - 1.f) * 0.5f;
        const int   yi = (int)fminf(fmaxf(rintf(fy), 0.f), (float)(V - 1));
        const float fx0 = ((gx[u] + 1e-6f + 1.f) * (float)D - 1.f) * 0.5f;
        #pragma unroll
        for (int sft = 0; sft < 2; ++sft) {
            const float fx = (sft == 0) ? (fx0 - 0.5f) : (fx0 + 0.5f);
            const int   xi = (int)fminf(fmaxf(rintf(fx), 0.f), (float)(D - 1));
            const float qc = ((float)xi + 0.5f) * (2.f / (float)D) - 1.f;
            rel[u][sft] = (gx[u] - qc) * (float)D;
            const __half* rec = sb + (size_t)(yi * D + xi) * RECH;
            ra[u][sft] = *(const uint4*)rec;
            rz[u][sft] = *(const unsigned*)(rec + 8);
        }
    }

    float bl00[4], bl01[4], bl10[4], bl11[4], wxv[4], wyv[4];
    #pragma unroll
    for (int u = 0; u < 4; ++u) {
        float fxb = fminf(fmaxf(((gx[u] + 1.f) * (float)D - 1.f) * 0.5f, 0.f), (float)(D - 1));
        float fyb = fminf(fmaxf(((gy[u] + 1.f) * (float)V - 1.f) * 0.5f, 0.f), (float)(V - 1));
        const float x0 = floorf(fxb), y0 = floorf(fyb);
        wxv[u] = fxb - x0; wyv[u] = fyb - y0;
        const int x0i = (int)x0, y0i = (int)y0;
        const int y1i = min(y0i + 1, V - 1);
        if (PAIRED) {
            const float2 t  = s2b[y0i * D + x0i];
            const float2 u2 = s2b[y1i * D + x0i];
            bl00[u] = t.x;  bl01[u] = t.y;
            bl10[u] = u2.x; bl11[u] = u2.y;
        } else {
            const int x1i = min(x0i + 1, D - 1);
            bl00[u] = sg[y0i * D + x0i]; bl01[u] = sg[y0i * D + x1i];
            bl10[u] = sg[y1i * D + x0i]; bl11[u] = sg[y1i * D + x1i];
        }
    }

    __builtin_amdgcn_sched_barrier(0);

    float acc = 0.f;
    #pragma unroll
    for (int u = 0; u < 4; ++u) {
        const float v0f = decode_rec(ra[u][0], (unsigned short)(rz[u][0] & 0xffffu), rel[u][0]);
        const float v1f = decode_rec(ra[u][1], (unsigned short)(rz[u][1] & 0xffffu), rel[u][1]);
        const float l0 = fabsf(rel[u][0]) + 1e-4f;
        const float l1 = fabsf(rel[u][1]) + 1e-4f;
        const float recon = (v0f * l1 + v1f * l0) / (l0 + l1);
        const float wx = wxv[u], wy = wyv[u];
        const float bp = bl00[u] * (1.f - wx) * (1.f - wy) + bl01[u] * wx * (1.f - wy)
                       + bl10[u] * (1.f - wx) * wy         + bl11[u] * wx * wy;
        acc += (recon + bp) * sv[u] * 1e4f;
    }
    __builtin_nontemporal_store(acc, partial + ((size_t)chunk * B + b) * P2 + p);
}

// ---------------------------------------------------------------------------
// Kernel 3: fold the NCHUNK partials
// ---------------------------------------------------------------------------
__global__ __launch_bounds__(256) void reduce_kernel(
    const float* __restrict__ partial, float* __restrict__ out)
{
    const int i = blockIdx.x * 256 + threadIdx.x;   // 0..B*P2-1
    float a = 0.f;
    #pragma unroll 6
    for (int c = 0; c < NCHUNK; ++c)
        a += __builtin_nontemporal_load(partial + (size_t)c * B * P2 + i);
    out[i] = a;
}

// ---------------------------------------------------------------------------
extern "C" void kernel_launch(void* const* d_in, const int* in_sizes, int n_in,
                              void* d_out, int out_size, void* d_ws, size_t ws_size,
                              hipStream_t stream)
{
    const float* sinogram = (const float*)d_in[0];
    const float* feat     = (const float*)d_in[1];
    const float* grid     = (const float*)d_in[2];
    const float* sq       = (const float*)d_in[3];
    const float* w        = (const float*)d_in[4];
    const float* bias     = (const float*)d_in[5];
    float* out = (float*)d_out;

    const size_t pair_b = (size_t)B * V * PENT * PENTB;              // 47.3 MB
    const size_t part_b = (size_t)NCHUNK * B * P2 * sizeof(float);   //  5.9 MB
    const size_t sg4_b  = (size_t)B * V * D * sizeof(float4);        // 11.8 MB
    const size_t sg2_b  = (size_t)B * V * D * sizeof(float2);        //  5.9 MB
    const size_t rec_b  = (size_t)B * V * D * RECH * sizeof(__half); // 23.6 MB

    if (ws_size >= pair_b + part_b + sg4_b) {
        // Tier 1: pair-entry table + 4-tap sinogram table
        char*   pair    = (char*)d_ws;
        float*  partial = (float*)((char*)d_ws + pair_b);
        float4* sg4     = (float4*)((char*)d_ws + pair_b + part_b);
        conv_kernel<1><<<dim3(720), 256, 0, stream>>>(feat, w, bias, pair);
        build_sg4<<<dim3(2880), 256, 0, stream>>>(sinogram, sg4);
        sample_pair<1><<<dim3(5760), 256, 0, stream>>>(pair, sg4, (const float2*)sg4, grid, sq, partial);
        reduce_kernel<<<dim3((B * P2) / 256), 256, 0, stream>>>(partial, out);
    } else if (ws_size >= pair_b + part_b + sg2_b) {
        // Tier 2: pair-entry table + 2-tap sinogram table
        char*   pair    = (char*)d_ws;
        float*  partial = (float*)((char*)d_ws + pair_b);
        float2* sg2     = (float2*)((char*)d_ws + pair_b + part_b);
        conv_kernel<1><<<dim3(720), 256, 0, stream>>>(feat, w, bias, pair);
        build_sg2<<<dim3(2880), 256, 0, stream>>>(sinogram, sg2);
        sample_pair<0><<<dim3(5760), 256, 0, stream>>>(pair, (const float4*)sg2, sg2, grid, sq, partial);
        reduce_kernel<<<dim3((B * P2) / 256), 256, 0, stream>>>(partial, out);
    } else if (ws_size >= rec_b + part_b + sg2_b) {
        // Tier 3: plain records + paired sinogram
        char*   sino    = (char*)d_ws;
        float*  partial = (float*)((char*)d_ws + rec_b);
        float2* sg2     = (float2*)((char*)d_ws + rec_b + part_b);
        conv_kernel<0><<<dim3(720), 256, 0, stream>>>(feat, w, bias, sino);
        build_sg2<<<dim3(2880), 256, 0, stream>>>(sinogram, sg2);
        sample_basic<1><<<dim3(5760), 256, 0, stream>>>((const __half*)sino, sinogram, sg2, grid, sq, partial);
        reduce_kernel<<<dim3((B * P2) / 256), 256, 0, stream>>>(partial, out);
    } else {
        // Tier 4: plain records, direct sinogram bilinear
        char*   sino    = (char*)d_ws;
        float*  partial = (float*)((char*)d_ws + rec_b);
        conv_kernel<0><<<dim3(720), 256, 0, stream>>>(feat, w, bias, sino);
        sample_basic<0><<<dim3(5760), 256, 0, stream>>>((const __half*)sino, sinogram, (const float2*)sino, grid, sq, partial);
        reduce_kernel<<<dim3((B * P2) / 256), 256, 0, stream>>>(partial, out);
    }
}